// Round 4
// baseline (647.352 us; speedup 1.0000x reference)
//
#include <hip/hip_runtime.h>
#include <stdint.h>

// DCN forward: B=4, H=128, W=128, G=8, C=32, K=8
// inputs      [B,H,W,G,C]   fp32
// deformables [B,H,W,G,K,2] fp32
// weights     [B,H,W,G,K]   fp32
// out         [B,H,W,G,C]   fp32
//
// R4: LDS-staged gather. Block = 8x8 pixel tile of one (b,g) plane,
// 512 threads (8 c4-lanes per pixel). Stage an 18x18-cell halo window
// (41.5 KB) into LDS, gather via ds_read_b128 (guaranteed hit, dedicated
// 128B/cyc pipe) instead of thrashing the 32 KB L1. Samples with
// |offset| >= 5 (P ~ 6e-7 for N(0,1)) take a global-memory fallback
// branch with identical math.

#define Bc 4
#define Hc 128
#define Wc 128
#define Gc 8
#define Cc 32
#define Kc 8
#define TH 8
#define TW 8
#define RH 5
#define WR (TH + 2*RH)    // 18 window rows
#define WCOL (TW + 2*RH)  // 18 window cols
#define NCELL (WR*WCOL)   // 324 cells * 128 B = 41472 B
#define NF4 (NCELL*8)     // 2592 float4 units

typedef float float4v __attribute__((ext_vector_type(4)));

__global__ __launch_bounds__(512, 6) void dcn_fwd(
    const float* __restrict__ inp,
    const float* __restrict__ def,
    const float* __restrict__ wts,
    float* __restrict__ out)
{
    const int tid = threadIdx.x;
    const int c4  = tid & 7;      // which float4 of the 32 channels
    const int p   = tid >> 3;     // 0..63 pixel slot
    const int pw  = p & 7;
    const int ph  = p >> 3;

    // grid: wt(16), ht(16), g(8), b(4)
    const int blk = blockIdx.x;
    const int wt = blk & 15;
    const int ht = (blk >> 4) & 15;
    const int g  = (blk >> 8) & 7;
    const int b  = blk >> 11;

    const int h0 = ht * TH, w0 = wt * TW;
    const int row0 = h0 - RH, col0 = w0 - RH;   // window origin (may be <0)

    // batch stride = H*W*G*C*4 = 1<<24 bytes; row stride = 1<<17; cell = 1<<10
    const char* gplane = (const char*)inp + ((size_t)b << 24) + ((size_t)g << 7);

    __shared__ float4v tile[NF4];

    // ---- stage 18x18 cell window (row/col clamped like the gather clamps) ----
    for (int ch = 0; ch < 6; ++ch) {
        const int idx = ch * 512 + tid;
        if (idx < NF4) {
            const int cell = idx >> 3;
            const int u    = idx & 7;
            const int r    = (cell * 3641) >> 16;   // exact cell/18 for cell<324
            const int c    = cell - r * WR;
            const int gr   = min(max(row0 + r, 0), Hc - 1);
            const int gc   = min(max(col0 + c, 0), Wc - 1);
            tile[idx] = *(const float4v*)(gplane + ((gr << 17) + (gc << 10) + (u << 4)));
        }
    }
    __syncthreads();

    const int h = h0 + ph;
    const int w = w0 + pw;
    const int pg = ((b * Hc + h) * Wc + w) * Gc + g;

    // vectorized def/wts loads
    const float4v d0 = *(const float4v*)(def + (size_t)pg * 16 + 0);
    const float4v d1 = *(const float4v*)(def + (size_t)pg * 16 + 4);
    const float4v d2 = *(const float4v*)(def + (size_t)pg * 16 + 8);
    const float4v d3 = *(const float4v*)(def + (size_t)pg * 16 + 12);
    const float4v q0 = *(const float4v*)(wts + (size_t)pg * 8 + 0);
    const float4v q1 = *(const float4v*)(wts + (size_t)pg * 8 + 4);

    const float dxs[8] = {d0.x, d0.z, d1.x, d1.z, d2.x, d2.z, d3.x, d3.z};
    const float dys[8] = {d0.y, d0.w, d1.y, d1.w, d2.y, d2.w, d3.y, d3.w};
    const float wks[8] = {q0.x, q0.y, q0.z, q0.w, q1.x, q1.y, q1.z, q1.w};

    const float wf = (float)w;
    const float hf = (float)h;

    // LDS gather base: addr = lb + ((yf*WR + xf) << 7)
    // folds c4 slice and -window-origin so per-corner math is mad+shl-add
    const int cellbase = row0 * WR + col0;
    const char* lb = (const char*)tile + (c4 << 4) - cellbase * 128;
    const char* gbase = gplane + (c4 << 4);   // fallback path base

    float4v acc0 = {0.f, 0.f, 0.f, 0.f};
    float4v acc1 = {0.f, 0.f, 0.f, 0.f};

#pragma unroll
    for (int k = 0; k < Kc; ++k) {
        const float dx = dxs[k];
        const float dy = dys[k];
        const float wk = wks[k];

        const float x = dx + wf;
        const float y = dy + hf;

        // truncation toward zero, matching .astype(int32)
        const int fx = (int)x;
        const int fy = (int)y;
        const int cx = fx + 1;
        const int cy = fy + 1;

        const float wx1 = x - (float)fx;
        const float wx0 = (float)cx - x;
        const float wy1 = y - (float)fy;
        const float wy0 = (float)cy - y;

        // in-bounds mask via unsigned compare
        const float ax0 = ((uint32_t)fx < (uint32_t)Wc) ? wx0 : 0.f;
        const float ax1 = ((uint32_t)cx < (uint32_t)Wc) ? wx1 : 0.f;
        const float ay0 = ((uint32_t)fy < (uint32_t)Hc) ? wy0 : 0.f;
        const float ay1 = ((uint32_t)cy < (uint32_t)Hc) ? wy1 : 0.f;

        // clamped gather coordinates
        const int xf = min(max(fx, 0), Wc - 1);
        const int xc = min(max(cx, 0), Wc - 1);
        const int yf = min(max(fy, 0), Hc - 1);
        const int yc = min(max(cy, 0), Hc - 1);

        // weights folded: wk into the y-axis terms first
        const float ay0k = wk * ay0;
        const float ay1k = wk * ay1;
        const float c00 = ay0k * ax0;
        const float c01 = ay0k * ax1;
        const float c10 = ay1k * ax0;
        const float c11 = ay1k * ax1;

        float4v v00, v01, v10, v11;
        const bool inh = (fabsf(dx) < (float)RH) && (fabsf(dy) < (float)RH);
        if (__builtin_expect(inh, 1)) {
            // window containment proven for |dx|,|dy| < RH incl. image-edge clamps
            const int ya = yf * WR;
            const int yb = yc * WR;
            v00 = *(const float4v*)(lb + ((ya + xf) << 7));
            v01 = *(const float4v*)(lb + ((ya + xc) << 7));
            v10 = *(const float4v*)(lb + ((yb + xf) << 7));
            v11 = *(const float4v*)(lb + ((yb + xc) << 7));
        } else {
            // rare fallback: direct global gather (identical semantics)
            v00 = *(const float4v*)(gbase + ((yf << 17) + (xf << 10)));
            v01 = *(const float4v*)(gbase + ((yf << 17) + (xc << 10)));
            v10 = *(const float4v*)(gbase + ((yc << 17) + (xf << 10)));
            v11 = *(const float4v*)(gbase + ((yc << 17) + (xc << 10)));
        }

        acc0 += c00 * v00;
        acc1 += c01 * v01;
        acc0 += c10 * v10;
        acc1 += c11 * v11;
    }

    const float4v acc = acc0 + acc1;
    *(float4v*)((char*)out + (size_t)pg * 128 + (c4 << 4)) = acc;
}

extern "C" void kernel_launch(void* const* d_in, const int* in_sizes, int n_in,
                              void* d_out, int out_size, void* d_ws, size_t ws_size,
                              hipStream_t stream) {
    const float* inp = (const float*)d_in[0];
    const float* def = (const float*)d_in[1];
    const float* wts = (const float*)d_in[2];
    float* out = (float*)d_out;

    const int nblocks = Bc * Gc * (Hc / TH) * (Wc / TW);  // 8192
    dcn_fwd<<<nblocks, 512, 0, stream>>>(inp, def, wts, out);
}

// Round 5
// 80.055 us; speedup vs baseline: 8.0863x; 8.0863x over previous
//
#include <hip/hip_runtime.h>
#include <stdint.h>

// DCN forward: B=4, H=128, W=128, G=8, C=32, K=8
// inputs      [B,H,W,G,C]   fp32
// deformables [B,H,W,G,K,2] fp32
// weights     [B,H,W,G,K]   fp32
// out         [B,H,W,G,C]   fp32
//
// R5: LDS-staged gather, fixed.
//  - typed LDS indexing only (no generic-pointer casts -> real ds_read_b128)
//  - cell-swizzled slot layout: float4 slot = (c4 + cell) & 7, breaking the
//    structural 8-way bank conflict of [cell][c4] (cell stride 1024B ≡ 0 mod 128)
//  - branchless common path; exact per-corner window containment; rare
//    global-gather correction branch (execz-skipped almost always)

#define Bc 4
#define Hc 128
#define Wc 128
#define Gc 8
#define Cc 32
#define Kc 8
#define TH 8
#define TW 8
#define RH 5
#define WR   (TH + 2*RH)   // 18 window rows
#define WCOL (TW + 2*RH)   // 18 window cols
#define NCELL (WR*WCOL)    // 324 cells
#define NF4  (NCELL*8)     // 2592 float4 units = 41472 B

typedef float float4v __attribute__((ext_vector_type(4)));

__global__ __launch_bounds__(512, 4) void dcn_fwd(
    const float* __restrict__ inp,
    const float* __restrict__ def,
    const float* __restrict__ wts,
    float* __restrict__ out)
{
    const int tid = threadIdx.x;
    const int c4  = tid & 7;      // which float4 of the 32 channels
    const int p   = tid >> 3;     // 0..63 pixel slot
    const int pw  = p & 7;
    const int ph  = p >> 3;

    // grid: wt(16), ht(16), g(8), b(4)
    const int blk = blockIdx.x;
    const int wt = blk & 15;
    const int ht = (blk >> 4) & 15;
    const int g  = (blk >> 8) & 7;
    const int b  = blk >> 11;

    const int h0 = ht * TH, w0 = wt * TW;
    const int row0 = h0 - RH, col0 = w0 - RH;   // window origin (may be <0)

    // global plane as float4 units: index = y*8192 + x*64 + u
    const float4v* gp4 = (const float4v*)((const char*)inp
        + ((size_t)b << 24) + ((size_t)g << 7));

    __shared__ float4v tile[NF4];

    // ---- stage 18x18 cell window, swizzled slot = (u + cell) & 7 ----
#pragma unroll
    for (int ch = 0; ch < 6; ++ch) {
        const int idx = ch * 512 + tid;
        if (idx < NF4) {
            const int cell = idx >> 3;
            const int u    = idx & 7;
            const int r    = (cell * 3641) >> 16;   // exact cell/18 for cell<324
            const int c    = cell - r * WR;
            const int gr   = min(max(row0 + r, 0), Hc - 1);
            const int gc   = min(max(col0 + c, 0), Wc - 1);
            tile[(cell << 3) + ((u + cell) & 7)] = gp4[gr * 8192 + gc * 64 + u];
        }
    }
    __syncthreads();

    const int h = h0 + ph;
    const int w = w0 + pw;
    const int pg = ((b * Hc + h) * Wc + w) * Gc + g;

    // vectorized def/wts loads
    const float4v d0 = *(const float4v*)(def + (size_t)pg * 16 + 0);
    const float4v d1 = *(const float4v*)(def + (size_t)pg * 16 + 4);
    const float4v d2 = *(const float4v*)(def + (size_t)pg * 16 + 8);
    const float4v d3 = *(const float4v*)(def + (size_t)pg * 16 + 12);
    const float4v q0 = *(const float4v*)(wts + (size_t)pg * 8 + 0);
    const float4v q1 = *(const float4v*)(wts + (size_t)pg * 8 + 4);

    const float dxs[8] = {d0.x, d0.z, d1.x, d1.z, d2.x, d2.z, d3.x, d3.z};
    const float dys[8] = {d0.y, d0.w, d1.y, d1.w, d2.y, d2.w, d3.y, d3.w};
    const float wks[8] = {q0.x, q0.y, q0.z, q0.w, q1.x, q1.y, q1.z, q1.w};

    const float wf = (float)w;
    const float hf = (float)h;

    float4v acc0 = {0.f, 0.f, 0.f, 0.f};
    float4v acc1 = {0.f, 0.f, 0.f, 0.f};

#pragma unroll
    for (int k = 0; k < Kc; ++k) {
        const float x = dxs[k] + wf;
        const float y = dys[k] + hf;

        // truncation toward zero, matching .astype(int32)
        const int fx = (int)x;
        const int fy = (int)y;
        const int cx = fx + 1;
        const int cy = fy + 1;

        const float wx1 = x - (float)fx;
        const float wx0 = (float)cx - x;
        const float wy1 = y - (float)fy;
        const float wy0 = (float)cy - y;

        // image-bounds mask via unsigned compare
        const float ax0 = ((uint32_t)fx < (uint32_t)Wc) ? wx0 : 0.f;
        const float ax1 = ((uint32_t)cx < (uint32_t)Wc) ? wx1 : 0.f;
        const float ay0 = ((uint32_t)fy < (uint32_t)Hc) ? wy0 : 0.f;
        const float ay1 = ((uint32_t)cy < (uint32_t)Hc) ? wy1 : 0.f;

        // clamped gather coordinates (image space)
        const int xf = min(max(fx, 0), Wc - 1);
        const int xc = min(max(cx, 0), Wc - 1);
        const int yf = min(max(fy, 0), Hc - 1);
        const int yc = min(max(cy, 0), Hc - 1);

        const float wk = wks[k];
        const float ay0k = wk * ay0;
        const float ay1k = wk * ay1;
        const float c00 = ay0k * ax0;
        const float c01 = ay0k * ax1;
        const float c10 = ay1k * ax0;
        const float c11 = ay1k * ax1;

        // window-relative coords; exact containment test
        const int ry0 = yf - row0, ry1 = yc - row0;
        const int rx0 = xf - col0, rx1 = xc - col0;
        const bool inh = (ry0 >= 0) & (rx0 >= 0) & (ry1 < WR) & (rx1 < WCOL);

        const int cl00 = ry0 * WCOL + rx0;
        const int cl01 = ry0 * WCOL + rx1;
        const int cl10 = ry1 * WCOL + rx0;
        const int cl11 = ry1 * WCOL + rx1;

        // safe LDS indices (idx c4 when out-of-window; weight is zeroed)
        const int i00 = inh ? ((cl00 << 3) + ((c4 + cl00) & 7)) : c4;
        const int i01 = inh ? ((cl01 << 3) + ((c4 + cl01) & 7)) : c4;
        const int i10 = inh ? ((cl10 << 3) + ((c4 + cl10) & 7)) : c4;
        const int i11 = inh ? ((cl11 << 3) + ((c4 + cl11) & 7)) : c4;

        const float l00 = inh ? c00 : 0.f;
        const float l01 = inh ? c01 : 0.f;
        const float l10 = inh ? c10 : 0.f;
        const float l11 = inh ? c11 : 0.f;

        acc0 += l00 * tile[i00];
        acc1 += l01 * tile[i01];
        acc0 += l10 * tile[i10];
        acc1 += l11 * tile[i11];

        if (__builtin_expect(!inh, 0)) {
            // rare: sample beyond the staged halo -> true global gather
            acc0 += c00 * gp4[yf * 8192 + xf * 64 + c4];
            acc1 += c01 * gp4[yf * 8192 + xc * 64 + c4];
            acc0 += c10 * gp4[yc * 8192 + xf * 64 + c4];
            acc1 += c11 * gp4[yc * 8192 + xc * 64 + c4];
        }
    }

    const float4v acc = acc0 + acc1;
    *(float4v*)((char*)out + (size_t)pg * 128 + (c4 << 4)) = acc;
}

extern "C" void kernel_launch(void* const* d_in, const int* in_sizes, int n_in,
                              void* d_out, int out_size, void* d_ws, size_t ws_size,
                              hipStream_t stream) {
    const float* inp = (const float*)d_in[0];
    const float* def = (const float*)d_in[1];
    const float* wts = (const float*)d_in[2];
    float* out = (float*)d_out;

    const int nblocks = Bc * Gc * (Hc / TH) * (Wc / TW);  // 8192
    dcn_fwd<<<nblocks, 512, 0, stream>>>(inp, def, wts, out);
}

// Round 6
// 60.423 us; speedup vs baseline: 10.7137x; 1.3249x over previous
//
#include <hip/hip_runtime.h>
#include <stdint.h>

// DCN forward: B=4, H=128, W=128, G=8, C=32, K=8
// inputs      [B,H,W,G,C]   fp32
// deformables [B,H,W,G,K,2] fp32
// weights     [B,H,W,G,K]   fp32
// out         [B,H,W,G,C]   fp32
//
// R6: LDS-staged gather, VALU-thinned.
//  - 4 lanes/pixel (2 float4 slots each) -> coordinate math duplicated 4x not 8x
//  - tile 8x16 px, halo window 18x26 cells = 58.5 KB LDS, 2 blocks/CU
//  - common path branch-free: min-clamped cell index, unconditional LDS FMA;
//    rare (!inh ~ 1e-6) correction branch subtracts the clamped-cell term and
//    adds the true global gather (identical reference semantics)
//  - slot swizzle (s + cell) & 7 as in R5

#define Bc 4
#define Hc 128
#define Wc 128
#define Gc 8
#define Cc 32
#define Kc 8
#define TH 8
#define TW 16
#define RH 5
#define WR   (TH + 2*RH)    // 18 window rows
#define WCOL (TW + 2*RH)    // 26 window cols
#define NCELL (WR*WCOL)     // 468 cells
#define NF4  (NCELL*8)      // 3744 float4 units = 59904 B

typedef float float4v __attribute__((ext_vector_type(4)));

__global__ __launch_bounds__(512, 4) void dcn_fwd(
    const float* __restrict__ inp,
    const float* __restrict__ def,
    const float* __restrict__ wts,
    float* __restrict__ out)
{
    const int tid = threadIdx.x;
    const int j   = tid & 3;       // lane owns float4 slots 2j, 2j+1
    const int px  = tid >> 2;      // 0..127 pixel slot in tile
    const int pw  = px & 15;
    const int ph  = px >> 4;

    // grid: wt(8), ht(16), g(8), b(4)
    const int blk = blockIdx.x;
    const int wt = blk & 7;
    const int ht = (blk >> 3) & 15;
    const int g  = (blk >> 7) & 7;
    const int b  = blk >> 10;

    const int h0 = ht * TH, w0 = wt * TW;
    const int row0 = h0 - RH, col0 = w0 - RH;   // window origin (may be <0)

    // global plane as float4 units: index = y*8192 + x*64 + u
    const float4v* gp4 = (const float4v*)((const char*)inp
        + ((size_t)b << 24) + ((size_t)g << 7));

    __shared__ float4v tile[NF4];

    // ---- stage 18x26 cell window, swizzled slot = (u + cell) & 7 ----
#pragma unroll
    for (int r = 0; r < 8; ++r) {
        const int idx = r * 512 + tid;
        if (idx < NF4) {
            const int cell = idx >> 3;
            const int u    = idx & 7;
            const int rr   = (cell * 2521) >> 16;   // exact cell/26 for cell<468
            const int cc   = cell - rr * WCOL;
            const int gr   = min(max(row0 + rr, 0), Hc - 1);
            const int gc   = min(max(col0 + cc, 0), Wc - 1);
            tile[(cell << 3) + ((u + cell) & 7)] = gp4[gr * 8192 + gc * 64 + u];
        }
    }
    __syncthreads();

    const int h = h0 + ph;
    const int w = w0 + pw;
    const int pg = ((b * Hc + h) * Wc + w) * Gc + g;

    // vectorized def/wts loads
    const float4v d0 = *(const float4v*)(def + (size_t)pg * 16 + 0);
    const float4v d1 = *(const float4v*)(def + (size_t)pg * 16 + 4);
    const float4v d2 = *(const float4v*)(def + (size_t)pg * 16 + 8);
    const float4v d3 = *(const float4v*)(def + (size_t)pg * 16 + 12);
    const float4v q0 = *(const float4v*)(wts + (size_t)pg * 8 + 0);
    const float4v q1 = *(const float4v*)(wts + (size_t)pg * 8 + 4);

    const float dxs[8] = {d0.x, d0.z, d1.x, d1.z, d2.x, d2.z, d3.x, d3.z};
    const float dys[8] = {d0.y, d0.w, d1.y, d1.w, d2.y, d2.w, d3.y, d3.w};
    const float wks[8] = {q0.x, q0.y, q0.z, q0.w, q1.x, q1.y, q1.z, q1.w};

    const float wf = (float)w;
    const float hf = (float)h;
    const int s0 = 2 * j;
    const int s1 = 2 * j + 1;

    float4v accA = {0.f, 0.f, 0.f, 0.f};
    float4v accB = {0.f, 0.f, 0.f, 0.f};

#pragma unroll
    for (int k = 0; k < Kc; ++k) {
        const float x = dxs[k] + wf;
        const float y = dys[k] + hf;

        // truncation toward zero, matching .astype(int32)
        const int fx = (int)x;
        const int fy = (int)y;
        const int cx = fx + 1;
        const int cy = fy + 1;

        const float wx1 = x - (float)fx;
        const float wx0 = (float)cx - x;
        const float wy1 = y - (float)fy;
        const float wy0 = (float)cy - y;

        // image-bounds mask via unsigned compare
        const float ax0 = ((uint32_t)fx < (uint32_t)Wc) ? wx0 : 0.f;
        const float ax1 = ((uint32_t)cx < (uint32_t)Wc) ? wx1 : 0.f;
        const float ay0 = ((uint32_t)fy < (uint32_t)Hc) ? wy0 : 0.f;
        const float ay1 = ((uint32_t)cy < (uint32_t)Hc) ? wy1 : 0.f;

        // clamped gather coordinates (image space)
        const int xf = min(max(fx, 0), Wc - 1);
        const int xc = min(max(cx, 0), Wc - 1);
        const int yf = min(max(fy, 0), Hc - 1);
        const int yc = min(max(cy, 0), Hc - 1);

        const float wk = wks[k];
        const float ay0k = wk * ay0;
        const float ay1k = wk * ay1;
        const float c00 = ay0k * ax0;
        const float c01 = ay0k * ax1;
        const float c10 = ay1k * ax0;
        const float c11 = ay1k * ax1;

        // window-relative cells; clamp into tile via unsigned min (negative wraps)
        const int ry0 = yf - row0, ry1 = yc - row0;
        const int rx0 = xf - col0, rx1 = xc - col0;
        const int cl00 = min((uint32_t)(ry0 * WCOL + rx0), (uint32_t)(NCELL - 1));
        const int cl01 = min((uint32_t)(ry0 * WCOL + rx1), (uint32_t)(NCELL - 1));
        const int cl10 = min((uint32_t)(ry1 * WCOL + rx0), (uint32_t)(NCELL - 1));
        const int cl11 = min((uint32_t)(ry1 * WCOL + rx1), (uint32_t)(NCELL - 1));

        const int i00a = (cl00 << 3) + ((s0 + cl00) & 7);
        const int i00b = (cl00 << 3) + ((s1 + cl00) & 7);
        const int i01a = (cl01 << 3) + ((s0 + cl01) & 7);
        const int i01b = (cl01 << 3) + ((s1 + cl01) & 7);
        const int i10a = (cl10 << 3) + ((s0 + cl10) & 7);
        const int i10b = (cl10 << 3) + ((s1 + cl10) & 7);
        const int i11a = (cl11 << 3) + ((s0 + cl11) & 7);
        const int i11b = (cl11 << 3) + ((s1 + cl11) & 7);

        accA += c00 * tile[i00a];
        accB += c00 * tile[i00b];
        accA += c01 * tile[i01a];
        accB += c01 * tile[i01b];
        accA += c10 * tile[i10a];
        accB += c10 * tile[i10b];
        accA += c11 * tile[i11a];
        accB += c11 * tile[i11b];

        // containment: all four window coords inside the staged halo?
        const bool inh = (((ry0 | rx0) >= 0) & (ry1 < WR) & (rx1 < WCOL));
        if (__builtin_expect(!inh, 0)) {
            // rare: subtract the clamped-cell contribution (same indices ->
            // exact same values, race-free) and add the true global gather
            accA -= c00 * tile[i00a];
            accB -= c00 * tile[i00b];
            accA -= c01 * tile[i01a];
            accB -= c01 * tile[i01b];
            accA -= c10 * tile[i10a];
            accB -= c10 * tile[i10b];
            accA -= c11 * tile[i11a];
            accB -= c11 * tile[i11b];
            accA += c00 * gp4[yf * 8192 + xf * 64 + s0];
            accB += c00 * gp4[yf * 8192 + xf * 64 + s1];
            accA += c01 * gp4[yf * 8192 + xc * 64 + s0];
            accB += c01 * gp4[yf * 8192 + xc * 64 + s1];
            accA += c10 * gp4[yc * 8192 + xf * 64 + s0];
            accB += c10 * gp4[yc * 8192 + xf * 64 + s1];
            accA += c11 * gp4[yc * 8192 + xc * 64 + s0];
            accB += c11 * gp4[yc * 8192 + xc * 64 + s1];
        }
    }

    float4v* op = (float4v*)((char*)out + (size_t)pg * 128);
    op[s0] = accA;
    op[s1] = accB;
}

extern "C" void kernel_launch(void* const* d_in, const int* in_sizes, int n_in,
                              void* d_out, int out_size, void* d_ws, size_t ws_size,
                              hipStream_t stream) {
    const float* inp = (const float*)d_in[0];
    const float* def = (const float*)d_in[1];
    const float* wts = (const float*)d_in[2];
    float* out = (float*)d_out;

    const int nblocks = Bc * Gc * (Hc / TH) * (Wc / TW);  // 4096
    dcn_fwd<<<nblocks, 512, 0, stream>>>(inp, def, wts, out);
}